// Round 4
// baseline (217.248 us; speedup 1.0000x reference)
//
#include <hip/hip_runtime.h>
#include <cstdint>
#include <cstddef>

#define NN 8192
#define NF 512
#define SPLITK 4

typedef __attribute__((ext_vector_type(8))) short bf16x8;
typedef __attribute__((ext_vector_type(4))) float f32x4;

__device__ __forceinline__ unsigned short f2bf_bits(float f) {
  unsigned u = __builtin_bit_cast(unsigned, f);
  u += 0x7FFFu + ((u >> 16) & 1u);   // round-to-nearest-even
  return (unsigned short)(u >> 16);
}

__device__ __forceinline__ bf16x8 cvt8(float4 a, float4 b) {
  bf16x8 r;
  r[0] = (short)f2bf_bits(a.x); r[1] = (short)f2bf_bits(a.y);
  r[2] = (short)f2bf_bits(a.z); r[3] = (short)f2bf_bits(a.w);
  r[4] = (short)f2bf_bits(b.x); r[5] = (short)f2bf_bits(b.y);
  r[6] = (short)f2bf_bits(b.z); r[7] = (short)f2bf_bits(b.w);
  return r;
}

__device__ __forceinline__ void gld_lds16(const void* g, void* l) {
  __builtin_amdgcn_global_load_lds(
      (const __attribute__((address_space(1))) unsigned int*)g,
      (__attribute__((address_space(3))) unsigned int*)l, 16, 0, 0);
}

// K0: deg[i] = 1 + sum_j adj[i][j]; dinv = rsqrt(deg). CVT: also write adj as bf16.
template <bool CVT>
__global__ void k_rowsum(const float* __restrict__ adj, float* __restrict__ dinv,
                         short* __restrict__ adjb) {
  const int row = blockIdx.x;
  const float4* p = (const float4*)(adj + (size_t)row * NN);
  short* ob = CVT ? (adjb + (size_t)row * NN) : nullptr;
  float s = 0.f;
#pragma unroll
  for (int j = 0; j < 8; ++j) {
    float4 v = p[j * 256 + threadIdx.x];
    s += (v.x + v.y) + (v.z + v.w);
    if (CVT) {
      ushort4 o;
      o.x = f2bf_bits(v.x); o.y = f2bf_bits(v.y);
      o.z = f2bf_bits(v.z); o.w = f2bf_bits(v.w);
      *(ushort4*)&ob[(size_t)(j * 256 + threadIdx.x) * 4] = o;
    }
  }
#pragma unroll
  for (int off = 32; off > 0; off >>= 1) s += __shfl_down(s, off, 64);
  __shared__ float red[4];
  if ((threadIdx.x & 63) == 0) red[threadIdx.x >> 6] = s;
  __syncthreads();
  if (threadIdx.x == 0) {
    float deg = red[0] + red[1] + red[2] + red[3] + 1.0f;
    dinv[row] = (deg > 0.f) ? (1.0f / sqrtf(deg)) : 0.f;
  }
}

// K2: transpose fp32 [rows][cols] -> bf16 [cols][rows]; optional row-scale by dinv[row]
template <bool SCALE>
__global__ void k_transpose(const float* __restrict__ src, int rows, int cols,
                            const float* __restrict__ dinv, short* __restrict__ dst) {
  __shared__ float tile[32][33];
  const int c0 = blockIdx.x * 32, r0 = blockIdx.y * 32;
  const int tx = threadIdx.x & 31, ty = threadIdx.x >> 5;
#pragma unroll
  for (int i = 0; i < 32; i += 8) {
    float v = src[(size_t)(r0 + ty + i) * cols + c0 + tx];
    if (SCALE) v *= dinv[r0 + ty + i];
    tile[ty + i][tx] = v;
  }
  __syncthreads();
#pragma unroll
  for (int i = 0; i < 32; i += 8)
    dst[(size_t)(c0 + ty + i) * rows + r0 + tx] = (short)f2bf_bits(tile[tx][ty + i]);
}

// k_gemm3: m97-structure split-K partial GEMM.  P[kz] = A[:, kz-slice] @ Bt^T.
// 256 thr / 4 waves (2x2), 128x128 tile, BK=64, single-buffer 32KB LDS,
// 2-barrier loop; latency hiding via 4-5 co-resident blocks/CU (the regime the
// 912 TF m103 measurement used).  A bf16 [M][K], Bt bf16 [N][K], out fp32.
__global__ __launch_bounds__(256, 4)
void k_gemm3(const short* __restrict__ Ab, const short* __restrict__ Bt,
             int N, int K, float* __restrict__ Pout) {
  __shared__ __align__(16) short As[128 * 64];
  __shared__ __align__(16) short Bs[128 * 64];
  const int tid = threadIdx.x;
  const int lane = tid & 63;
  const int w = tid >> 6;
  const int wm = w >> 1, wn = w & 1;

  const int bid = blockIdx.y * gridDim.x + blockIdx.x;
  const int nb = gridDim.x * gridDim.y;
  const int sbid = ((nb & 7) == 0) ? ((bid & 7) * (nb >> 3) + (bid >> 3)) : bid;
  const int n0 = (sbid % gridDim.x) * 128;
  const int m0 = (sbid / gridDim.x) * 128;
  const int kz = blockIdx.z;
  const int ksl = K / SPLITK;                      // 2048
  const int kbase = kz * ksl;
  const int nt = ksl >> 6;                         // 32
  float* Cp = Pout + (size_t)kz * ((size_t)NN * N);

  f32x4 acc[4][4];
#pragma unroll
  for (int m = 0; m < 4; ++m)
#pragma unroll
    for (int n = 0; n < 4; ++n) acc[m][n] = (f32x4){0.f, 0.f, 0.f, 0.f};

  const int lr = lane & 15, kg = lane >> 4;

  for (int t = 0; t < nt; ++t) {
    const int kofs = kbase + (t << 6);
    // stage A and B tiles (4 gld_lds each per wave), XOR chunk-swizzle via source
#pragma unroll
    for (int q = 0; q < 4; ++q) {
      const int rblk = (w << 5) + (q << 3);        // wave-uniform LDS row base
      const int r = rblk + (lane >> 3);
      const int sc = (lane & 7) ^ (r & 7);
      gld_lds16(Ab + (size_t)(m0 + r) * K + kofs + (sc << 3), &As[rblk << 6]);
      gld_lds16(Bt + (size_t)(n0 + r) * K + kofs + (sc << 3), &Bs[rblk << 6]);
    }
    __syncthreads();                               // drains vmcnt -> tile resident
#pragma unroll
    for (int kk = 0; kk < 2; ++kk) {
      const int lc = (kk << 2) + kg;
      bf16x8 a[4], b[4];
#pragma unroll
      for (int m = 0; m < 4; ++m) {
        const int r = (wm << 6) + (m << 4) + lr;
        a[m] = *(const bf16x8*)&As[(r << 6) + ((lc ^ (r & 7)) << 3)];
      }
#pragma unroll
      for (int n = 0; n < 4; ++n) {
        const int r = (wn << 6) + (n << 4) + lr;
        b[n] = *(const bf16x8*)&Bs[(r << 6) + ((lc ^ (r & 7)) << 3)];
      }
#pragma unroll
      for (int m = 0; m < 4; ++m)
#pragma unroll
        for (int n = 0; n < 4; ++n)
          acc[m][n] = __builtin_amdgcn_mfma_f32_16x16x32_bf16(a[m], b[n], acc[m][n], 0, 0, 0);
    }
    __syncthreads();                               // before next overwrite
  }

  const int cl = lane & 15, rg = lane >> 4;
#pragma unroll
  for (int m = 0; m < 4; ++m)
#pragma unroll
    for (int n = 0; n < 4; ++n)
#pragma unroll
      for (int j = 0; j < 4; ++j) {
        const int gi = m0 + (wm << 6) + (m << 4) + (rg << 2) + j;
        const int gn = n0 + (wn << 6) + (n << 4) + cl;
        Cp[(size_t)gi * N + gn] = acc[m][n][j];
      }
}

// k_reduce: Hb[i][n] = bf16( d_i * sum_kz P[kz][i][n] + d_i^2 * feat[i][n] )
__global__ void k_reduce(const float* __restrict__ P, const float* __restrict__ dinv,
                         const float* __restrict__ feat, short* __restrict__ Hb) {
  const size_t idx = ((size_t)blockIdx.x * 256 + threadIdx.x) * 4;
  const int i = (int)(idx >> 9);
  const size_t stride = (size_t)NN * NF;
  float4 s = *(const float4*)&P[idx];
#pragma unroll
  for (int kz = 1; kz < SPLITK; ++kz) {
    float4 p = *(const float4*)&P[kz * stride + idx];
    s.x += p.x; s.y += p.y; s.z += p.z; s.w += p.w;
  }
  const float d = dinv[i], d2 = d * d;
  float4 f = *(const float4*)&feat[idx];
  ushort4 o;
  o.x = f2bf_bits(d * s.x + d2 * f.x);
  o.y = f2bf_bits(d * s.y + d2 * f.y);
  o.z = f2bf_bits(d * s.z + d2 * f.z);
  o.w = f2bf_bits(d * s.w + d2 * f.w);
  *(ushort4*)&Hb[idx] = o;
}

// k_gemm2: 8-wave pipelined 128x128 GEMM (round-3 version), used for GEMM2
// (K=512) and as the no-workspace fallback for GEMM1.
template <bool A_BF16, bool GCN_EPI>
__global__ __launch_bounds__(512, 2)
void k_gemm2(const void* __restrict__ Ap, const short* __restrict__ Bt,
             int N, int K,
             const float* __restrict__ dinv, const float* __restrict__ feat,
             void* __restrict__ Cp) {
  __shared__ __align__(16) short As[4][128 * 64];
  __shared__ __align__(16) short Bs[4][128 * 64];
  const int tid = threadIdx.x;
  const int lane = tid & 63;
  const int w = tid >> 6;
  const int wm = (w >> 1) & 1, wn = w & 1, kk = w >> 2;

  const int bid = blockIdx.y * gridDim.x + blockIdx.x;
  const int nb = gridDim.x * gridDim.y;
  const int sbid = ((nb & 7) == 0) ? ((bid & 7) * (nb >> 3) + (bid >> 3)) : bid;
  const int n0 = (sbid % gridDim.x) * 128;
  const int m0 = (sbid / gridDim.x) * 128;
  const int nt = K >> 6;

  f32x4 acc[4][4];
#pragma unroll
  for (int m = 0; m < 4; ++m)
#pragma unroll
    for (int n = 0; n < 4; ++n) acc[m][n] = (f32x4){0.f, 0.f, 0.f, 0.f};

  const int lr = lane & 15, kg = lane >> 4;
  const int lc = (kk << 2) + kg;

  auto stage_b = [&](int buf, int t) {
    const int kofs = t << 6;
#pragma unroll
    for (int q = 0; q < 2; ++q) {
      const int rblk = (w << 4) + (q << 3);
      const int r = rblk + (lane >> 3);
      const int sc = (lane & 7) ^ (r & 7);
      gld_lds16(Bt + (size_t)(n0 + r) * K + kofs + (sc << 3), &Bs[buf][rblk << 6]);
    }
  };
  auto stage_a = [&](int buf, int t) {
    const int kofs = t << 6;
    const short* Ab = (const short*)Ap;
#pragma unroll
    for (int q = 0; q < 2; ++q) {
      const int rblk = (w << 4) + (q << 3);
      const int r = rblk + (lane >> 3);
      const int sc = (lane & 7) ^ (r & 7);
      gld_lds16(Ab + (size_t)(m0 + r) * K + kofs + (sc << 3), &As[buf][rblk << 6]);
    }
  };
  auto stage_a_f32 = [&](int buf, int t) {
    const int kofs = t << 6;
    const float* Af = (const float*)Ap;
    const int r = tid >> 2;
    const int c0 = (tid & 3) << 4;
    const float* s = Af + (size_t)(m0 + r) * K + kofs + c0;
    float4 x0 = ((const float4*)s)[0], x1 = ((const float4*)s)[1];
    float4 x2 = ((const float4*)s)[2], x3 = ((const float4*)s)[3];
    const int cc = (tid & 3) << 1;
    *(bf16x8*)&As[buf][(r << 6) + ((cc ^ (r & 7)) << 3)]       = cvt8(x0, x1);
    *(bf16x8*)&As[buf][(r << 6) + (((cc + 1) ^ (r & 7)) << 3)] = cvt8(x2, x3);
  };
  auto read_a = [&](int buf, bf16x8* a) {
#pragma unroll
    for (int m = 0; m < 4; ++m) {
      const int r = (wm << 6) + (m << 4) + lr;
      a[m] = *(const bf16x8*)&As[buf][(r << 6) + ((lc ^ (r & 7)) << 3)];
    }
  };
  auto read_b2 = [&](int buf, int nh, bf16x8* b) {
#pragma unroll
    for (int i = 0; i < 2; ++i) {
      const int r = (wn << 6) + (((nh << 1) + i) << 4) + lr;
      b[i] = *(const bf16x8*)&Bs[buf][(r << 6) + ((lc ^ (r & 7)) << 3)];
    }
  };
  auto mfma8 = [&](bf16x8* a, bf16x8* b, int nh) {
#pragma unroll
    for (int m = 0; m < 4; ++m)
#pragma unroll
      for (int i = 0; i < 2; ++i)
        acc[m][(nh << 1) + i] =
            __builtin_amdgcn_mfma_f32_16x16x32_bf16(a[m], b[i], acc[m][(nh << 1) + i], 0, 0, 0);
  };

  if constexpr (A_BF16) {
    stage_a(0, 0); stage_b(0, 0);
    stage_a(1, 1); stage_b(1, 1);
    asm volatile("s_waitcnt vmcnt(4)" ::: "memory");
    __builtin_amdgcn_s_barrier();
    __builtin_amdgcn_sched_barrier(0);
    for (int t = 0; t < nt; ++t) {
      const int cur = t & 3;
      const bool more = (t + 2 < nt);
      bf16x8 a[4], b0[2], b1[2];
      read_a(cur, a);
      read_b2(cur, 0, b0);
      if (more) stage_a((t + 2) & 3, t + 2);
      __builtin_amdgcn_s_barrier();
      asm volatile("s_waitcnt lgkmcnt(0)" ::: "memory");
      __builtin_amdgcn_sched_barrier(0);
      __builtin_amdgcn_s_setprio(1);
      mfma8(a, b0, 0);
      __builtin_amdgcn_s_setprio(0);
      __builtin_amdgcn_sched_barrier(0);
      read_b2(cur, 1, b1);
      if (more) stage_b((t + 2) & 3, t + 2);
      asm volatile("s_waitcnt lgkmcnt(0)" ::: "memory");
      __builtin_amdgcn_sched_barrier(0);
      __builtin_amdgcn_s_setprio(1);
      mfma8(a, b1, 1);
      __builtin_amdgcn_s_setprio(0);
      __builtin_amdgcn_sched_barrier(0);
      if (more)            asm volatile("s_waitcnt vmcnt(4)" ::: "memory");
      else if (t + 1 < nt) asm volatile("s_waitcnt vmcnt(0)" ::: "memory");
      __builtin_amdgcn_s_barrier();
      __builtin_amdgcn_sched_barrier(0);
    }
  } else {
    stage_a_f32(0, 0); stage_b(0, 0);
    stage_a_f32(1, 1); stage_b(1, 1);
    __syncthreads();
    for (int t = 0; t < nt; ++t) {
      const int cur = t & 3;
      if (t + 2 < nt) { stage_a_f32((t + 2) & 3, t + 2); stage_b((t + 2) & 3, t + 2); }
      bf16x8 a[4], b0[2], b1[2];
      read_a(cur, a); read_b2(cur, 0, b0); read_b2(cur, 1, b1);
      __builtin_amdgcn_s_setprio(1);
      mfma8(a, b0, 0); mfma8(a, b1, 1);
      __builtin_amdgcn_s_setprio(0);
      __syncthreads();
    }
  }

  __syncthreads();
  float* red = (float*)&As[0][0];
  if (w >= 4) {
    float* my = red + ((w - 4) << 12);
#pragma unroll
    for (int m = 0; m < 4; ++m)
#pragma unroll
      for (int n = 0; n < 4; ++n)
        *(f32x4*)&my[(((m << 2) + n) << 8) + (lane << 2)] = acc[m][n];
  }
  __syncthreads();
  if (w < 4) {
    float* my = red + (w << 12);
#pragma unroll
    for (int m = 0; m < 4; ++m)
#pragma unroll
      for (int n = 0; n < 4; ++n)
        acc[m][n] += *(const f32x4*)&my[(((m << 2) + n) << 8) + (lane << 2)];
    const int cl = lane & 15, rg = lane >> 4;
#pragma unroll
    for (int m = 0; m < 4; ++m)
#pragma unroll
      for (int n = 0; n < 4; ++n)
#pragma unroll
        for (int j = 0; j < 4; ++j) {
          const int gi = m0 + (wm << 6) + (m << 4) + (rg << 2) + j;
          const int gn = n0 + (wn << 6) + (n << 4) + cl;
          const float v = acc[m][n][j];
          if constexpr (GCN_EPI) {
            const float d = dinv[gi];
            const float hv = d * v + d * d * feat[(size_t)gi * NF + gn];
            ((unsigned short*)Cp)[(size_t)gi * N + gn] = f2bf_bits(hv);
          } else {
            ((float*)Cp)[(size_t)gi * N + gn] = v;
          }
        }
  }
}

extern "C" void kernel_launch(void* const* d_in, const int* in_sizes, int n_in,
                              void* d_out, int out_size, void* d_ws, size_t ws_size,
                              hipStream_t stream) {
  const float* adj  = (const float*)d_in[0];
  const float* feat = (const float*)d_in[1];
  const float* W    = (const float*)d_in[2];

  // ws: dinv 32KB | FbT 8MB | WbT 512KB | Hb 8MB | adjb 128MB | partials 64MB
  char* ws = (char*)d_ws;
  float* dinv = (float*)ws;
  short* FbT  = (short*)(ws + 32768);
  short* WbT  = (short*)(ws + 32768 + 8388608);
  short* Hb   = (short*)(ws + 32768 + 8388608 + 524288);
  short* adjb = (short*)(ws + 32768 + 8388608 + 524288 + 8388608);
  float* part = (float*)(ws + 32768 + 8388608 + 524288 + 8388608 + 134217728);
  float* out  = (float*)d_out;
  const size_t need = (size_t)32768 + 8388608 + 524288 + 8388608 + 134217728 +
                      (size_t)SPLITK * NN * NF * 4;
  const bool big_ws = ws_size >= need;

  if (big_ws) {
    k_rowsum<true><<<NN, 256, 0, stream>>>(adj, dinv, adjb);
  } else {
    k_rowsum<false><<<NN, 256, 0, stream>>>(adj, dinv, nullptr);
  }
  k_transpose<true ><<<dim3(NF / 32, NN / 32), 256, 0, stream>>>(feat, NN, NF, dinv, FbT);
  k_transpose<false><<<dim3(NF / 32, NF / 32), 256, 0, stream>>>(W, NF, NF, nullptr, WbT);

  if (big_ws) {
    k_gemm3<<<dim3(NF / 128, NN / 128, SPLITK), 256, 0, stream>>>(adjb, FbT, NF, NN, part);
    k_reduce<<<(NN * NF) / (256 * 4), 256, 0, stream>>>(part, dinv, feat, Hb);
  } else {
    k_gemm2<false, true><<<dim3(NF / 128, NN / 128), 512, 0, stream>>>(
        adj, FbT, NF, NN, dinv, feat, Hb);
  }
  k_gemm2<true, false><<<dim3(NF / 128, NN / 128), 512, 0, stream>>>(
      Hb, WbT, NF, NF, nullptr, nullptr, out);
}

// Round 5
// 194.517 us; speedup vs baseline: 1.1169x; 1.1169x over previous
//
#include <hip/hip_runtime.h>
#include <cstdint>
#include <cstddef>

#define NN 8192
#define NF 512
#define SPLITK 4

typedef __attribute__((ext_vector_type(8))) short bf16x8;
typedef __attribute__((ext_vector_type(4))) float f32x4;

__device__ __forceinline__ unsigned short f2bf_bits(float f) {
  unsigned u = __builtin_bit_cast(unsigned, f);
  u += 0x7FFFu + ((u >> 16) & 1u);   // round-to-nearest-even
  return (unsigned short)(u >> 16);
}

__device__ __forceinline__ bf16x8 cvt8(float4 a, float4 b) {
  bf16x8 r;
  r[0] = (short)f2bf_bits(a.x); r[1] = (short)f2bf_bits(a.y);
  r[2] = (short)f2bf_bits(a.z); r[3] = (short)f2bf_bits(a.w);
  r[4] = (short)f2bf_bits(b.x); r[5] = (short)f2bf_bits(b.y);
  r[6] = (short)f2bf_bits(b.z); r[7] = (short)f2bf_bits(b.w);
  return r;
}

__device__ __forceinline__ void gld_lds16(const void* g, void* l) {
  __builtin_amdgcn_global_load_lds(
      (const __attribute__((address_space(1))) unsigned int*)g,
      (__attribute__((address_space(3))) unsigned int*)l, 16, 0, 0);
}

// K0: deg[i] = 1 + sum_j adj[i][j]; dinv = rsqrt(deg). CVT: also write adj as bf16.
template <bool CVT>
__global__ void k_rowsum(const float* __restrict__ adj, float* __restrict__ dinv,
                         short* __restrict__ adjb) {
  const int row = blockIdx.x;
  const float4* p = (const float4*)(adj + (size_t)row * NN);
  short* ob = CVT ? (adjb + (size_t)row * NN) : nullptr;
  float s = 0.f;
#pragma unroll
  for (int j = 0; j < 8; ++j) {
    float4 v = p[j * 256 + threadIdx.x];
    s += (v.x + v.y) + (v.z + v.w);
    if (CVT) {
      ushort4 o;
      o.x = f2bf_bits(v.x); o.y = f2bf_bits(v.y);
      o.z = f2bf_bits(v.z); o.w = f2bf_bits(v.w);
      *(ushort4*)&ob[(size_t)(j * 256 + threadIdx.x) * 4] = o;
    }
  }
#pragma unroll
  for (int off = 32; off > 0; off >>= 1) s += __shfl_down(s, off, 64);
  __shared__ float red[4];
  if ((threadIdx.x & 63) == 0) red[threadIdx.x >> 6] = s;
  __syncthreads();
  if (threadIdx.x == 0) {
    float deg = red[0] + red[1] + red[2] + red[3] + 1.0f;
    dinv[row] = (deg > 0.f) ? (1.0f / sqrtf(deg)) : 0.f;
  }
}

// K2: transpose fp32 [rows][cols] -> bf16 [cols][rows]; optional row-scale by dinv[row]
template <bool SCALE>
__global__ void k_transpose(const float* __restrict__ src, int rows, int cols,
                            const float* __restrict__ dinv, short* __restrict__ dst) {
  __shared__ float tile[32][33];
  const int c0 = blockIdx.x * 32, r0 = blockIdx.y * 32;
  const int tx = threadIdx.x & 31, ty = threadIdx.x >> 5;
#pragma unroll
  for (int i = 0; i < 32; i += 8) {
    float v = src[(size_t)(r0 + ty + i) * cols + c0 + tx];
    if (SCALE) v *= dinv[r0 + ty + i];
    tile[ty + i][tx] = v;
  }
  __syncthreads();
#pragma unroll
  for (int i = 0; i < 32; i += 8)
    dst[(size_t)(c0 + ty + i) * rows + r0 + tx] = (short)f2bf_bits(tile[tx][ty + i]);
}

// k_gemm8: 8-phase-style 256x256 split-K GEMM (m201 template, 4 phases per BK=64
// K-tile = 8 per 2 tiles).  P[kz] = A[:, kz] @ Bt^T.  512 thr / 8 waves (2M x 4N),
// per-wave out 128x64.  LDS = 2dbuf x 2khalf x [256][32] bf16 x {A,B} = 128 KB.
// 64B rows are bank-uniform for both gld_lds writes and b128 frag reads -> no swizzle.
// Counted vmcnt(4) at P0/P2 (per-wave queue oscillates 4-8, never drained).
__global__ __launch_bounds__(512, 2)
void k_gemm8(const short* __restrict__ Ab, const short* __restrict__ Bt,
             int N, int K, float* __restrict__ Pout) {
  __shared__ __align__(16) short As[2][2][256 * 32];
  __shared__ __align__(16) short Bs[2][2][256 * 32];
  const int tid = threadIdx.x, lane = tid & 63, w = tid >> 6;
  const int wm = w >> 2, wn = w & 3;           // 2M x 4N wave grid
  const int m0 = blockIdx.y * 256, n0 = blockIdx.x * 256;
  const int kz = blockIdx.z;
  const int ksl = K / SPLITK;
  const int kbase = kz * ksl;
  const int nt = ksl >> 6;
  float* Cp = Pout + (size_t)kz * ((size_t)NN * (size_t)N);

  f32x4 acc[8][4];
#pragma unroll
  for (int m = 0; m < 8; ++m)
#pragma unroll
    for (int n = 0; n < 4; ++n) acc[m][n] = (f32x4){0.f, 0.f, 0.f, 0.f};

  const int lr = lane & 15, kg = lane >> 4;

  // stage half h (k-cols h*32..h*32+31) of K-tile t into buf: 2 gld_lds per wave
  auto stageA = [&](int buf, int t, int h) {
    const int kofs = kbase + (t << 6) + (h << 5) + ((lane & 3) << 3);
#pragma unroll
    for (int rnd = 0; rnd < 2; ++rnd) {
      const int rowb = (rnd << 7) + (w << 4);                    // wave-uniform
      const int row = rowb + (lane >> 2);
      gld_lds16(Ab + (size_t)(m0 + row) * K + kofs, &As[buf][h][rowb << 5]);
    }
  };
  auto stageB = [&](int buf, int t, int h) {
    const int kofs = kbase + (t << 6) + (h << 5) + ((lane & 3) << 3);
#pragma unroll
    for (int rnd = 0; rnd < 2; ++rnd) {
      const int rowb = (rnd << 7) + (w << 4);
      const int row = rowb + (lane >> 2);
      gld_lds16(Bt + (size_t)(n0 + row) * K + kofs, &Bs[buf][h][rowb << 5]);
    }
  };
  auto readA = [&](int buf, int kh, bf16x8* a) {
#pragma unroll
    for (int mf = 0; mf < 8; ++mf)
      a[mf] = *(const bf16x8*)&As[buf][kh][(((wm << 7) + (mf << 4) + lr) << 5) + (kg << 3)];
  };
  auto readB2 = [&](int buf, int kh, int nh, bf16x8* b) {
#pragma unroll
    for (int i = 0; i < 2; ++i)
      b[i] = *(const bf16x8*)&Bs[buf][kh][(((wn << 6) + (((nh << 1) + i) << 4) + lr) << 5) + (kg << 3)];
  };
  auto mfma16 = [&](bf16x8* a, bf16x8* b, int nh) {
#pragma unroll
    for (int mf = 0; mf < 8; ++mf)
#pragma unroll
      for (int i = 0; i < 2; ++i)
        acc[mf][(nh << 1) + i] =
            __builtin_amdgcn_mfma_f32_16x16x32_bf16(a[mf], b[i], acc[mf][(nh << 1) + i], 0, 0, 0);
  };

  // prologue: tile 0's 4 half-tiles, order Ah0,Bh0,Ah1,Bh1 (matches vmcnt math)
  stageA(0, 0, 0); stageB(0, 0, 0); stageA(0, 0, 1); stageB(0, 0, 1);

  for (int t = 0; t < nt; ++t) {
    const int cur = t & 1, nxt = cur ^ 1;
    const bool more = (t + 1 < nt);
    bf16x8 a[8], b0[2], b1[2];
    // ---- P0: khalf 0, n01 ----
    asm volatile("s_waitcnt vmcnt(4)" ::: "memory");   // drain Ah0_c, Bh0_c
    __builtin_amdgcn_s_barrier();
    __builtin_amdgcn_sched_barrier(0);
    readA(cur, 0, a);
    readB2(cur, 0, 0, b0);
    if (more) stageA(nxt, t + 1, 0);
    asm volatile("s_waitcnt lgkmcnt(0)" ::: "memory");
    __builtin_amdgcn_sched_barrier(0);
    __builtin_amdgcn_s_setprio(1);
    mfma16(a, b0, 0);
    __builtin_amdgcn_s_setprio(0);
    __builtin_amdgcn_sched_barrier(0);
    // ---- P1: khalf 0, n23 ----
    __builtin_amdgcn_s_barrier();
    __builtin_amdgcn_sched_barrier(0);
    readB2(cur, 0, 1, b1);
    if (more) stageB(nxt, t + 1, 0);
    asm volatile("s_waitcnt lgkmcnt(0)" ::: "memory");
    __builtin_amdgcn_sched_barrier(0);
    __builtin_amdgcn_s_setprio(1);
    mfma16(a, b1, 1);
    __builtin_amdgcn_s_setprio(0);
    __builtin_amdgcn_sched_barrier(0);
    // ---- P2: khalf 1, n01 ----
    if (more) asm volatile("s_waitcnt vmcnt(4)" ::: "memory");  // drain Ah1_c, Bh1_c
    else      asm volatile("s_waitcnt vmcnt(0)" ::: "memory");
    __builtin_amdgcn_s_barrier();
    __builtin_amdgcn_sched_barrier(0);
    readA(cur, 1, a);
    readB2(cur, 1, 0, b0);
    if (more) stageA(nxt, t + 1, 1);
    asm volatile("s_waitcnt lgkmcnt(0)" ::: "memory");
    __builtin_amdgcn_sched_barrier(0);
    __builtin_amdgcn_s_setprio(1);
    mfma16(a, b0, 0);
    __builtin_amdgcn_s_setprio(0);
    __builtin_amdgcn_sched_barrier(0);
    // ---- P3: khalf 1, n23 ----
    __builtin_amdgcn_s_barrier();
    __builtin_amdgcn_sched_barrier(0);
    readB2(cur, 1, 1, b1);
    if (more) stageB(nxt, t + 1, 1);
    asm volatile("s_waitcnt lgkmcnt(0)" ::: "memory");
    __builtin_amdgcn_sched_barrier(0);
    __builtin_amdgcn_s_setprio(1);
    mfma16(a, b1, 1);
    __builtin_amdgcn_s_setprio(0);
    __builtin_amdgcn_sched_barrier(0);
  }

  // epilogue: C/D layout col=lane&15, row=(lane>>4)*4+j  [m89-verified]
  const int cl = lane & 15, rg = lane >> 4;
#pragma unroll
  for (int mf = 0; mf < 8; ++mf)
#pragma unroll
    for (int nf = 0; nf < 4; ++nf)
#pragma unroll
      for (int j = 0; j < 4; ++j) {
        const int gi = m0 + (wm << 7) + (mf << 4) + (rg << 2) + j;
        const int gn = n0 + (wn << 6) + (nf << 4) + cl;
        Cp[(size_t)gi * N + gn] = acc[mf][nf][j];
      }
}

// k_reduce: Hb[i][n] = bf16( d_i * sum_kz P[kz][i][n] + d_i^2 * feat[i][n] )
__global__ void k_reduce(const float* __restrict__ P, const float* __restrict__ dinv,
                         const float* __restrict__ feat, short* __restrict__ Hb) {
  const size_t idx = ((size_t)blockIdx.x * 256 + threadIdx.x) * 4;
  const int i = (int)(idx >> 9);
  const size_t stride = (size_t)NN * NF;
  float4 s = *(const float4*)&P[idx];
#pragma unroll
  for (int kz = 1; kz < SPLITK; ++kz) {
    float4 p = *(const float4*)&P[kz * stride + idx];
    s.x += p.x; s.y += p.y; s.z += p.z; s.w += p.w;
  }
  const float d = dinv[i], d2 = d * d;
  float4 f = *(const float4*)&feat[idx];
  ushort4 o;
  o.x = f2bf_bits(d * s.x + d2 * f.x);
  o.y = f2bf_bits(d * s.y + d2 * f.y);
  o.z = f2bf_bits(d * s.z + d2 * f.z);
  o.w = f2bf_bits(d * s.w + d2 * f.w);
  *(ushort4*)&Hb[idx] = o;
}

// k_gemm2: 8-wave pipelined 128x128 GEMM (round-3 version) for GEMM2 (K=512)
// and the no-workspace fallback for GEMM1.
template <bool A_BF16, bool GCN_EPI>
__global__ __launch_bounds__(512, 2)
void k_gemm2(const void* __restrict__ Ap, const short* __restrict__ Bt,
             int N, int K,
             const float* __restrict__ dinv, const float* __restrict__ feat,
             void* __restrict__ Cp) {
  __shared__ __align__(16) short As[4][128 * 64];
  __shared__ __align__(16) short Bs[4][128 * 64];
  const int tid = threadIdx.x;
  const int lane = tid & 63;
  const int w = tid >> 6;
  const int wm = (w >> 1) & 1, wn = w & 1, kk = w >> 2;

  const int bid = blockIdx.y * gridDim.x + blockIdx.x;
  const int nb = gridDim.x * gridDim.y;
  const int sbid = ((nb & 7) == 0) ? ((bid & 7) * (nb >> 3) + (bid >> 3)) : bid;
  const int n0 = (sbid % gridDim.x) * 128;
  const int m0 = (sbid / gridDim.x) * 128;
  const int nt = K >> 6;

  f32x4 acc[4][4];
#pragma unroll
  for (int m = 0; m < 4; ++m)
#pragma unroll
    for (int n = 0; n < 4; ++n) acc[m][n] = (f32x4){0.f, 0.f, 0.f, 0.f};

  const int lr = lane & 15, kg = lane >> 4;
  const int lc = (kk << 2) + kg;

  auto stage_b = [&](int buf, int t) {
    const int kofs = t << 6;
#pragma unroll
    for (int q = 0; q < 2; ++q) {
      const int rblk = (w << 4) + (q << 3);
      const int r = rblk + (lane >> 3);
      const int sc = (lane & 7) ^ (r & 7);
      gld_lds16(Bt + (size_t)(n0 + r) * K + kofs + (sc << 3), &Bs[buf][rblk << 6]);
    }
  };
  auto stage_a = [&](int buf, int t) {
    const int kofs = t << 6;
    const short* Ab = (const short*)Ap;
#pragma unroll
    for (int q = 0; q < 2; ++q) {
      const int rblk = (w << 4) + (q << 3);
      const int r = rblk + (lane >> 3);
      const int sc = (lane & 7) ^ (r & 7);
      gld_lds16(Ab + (size_t)(m0 + r) * K + kofs + (sc << 3), &As[buf][rblk << 6]);
    }
  };
  auto stage_a_f32 = [&](int buf, int t) {
    const int kofs = t << 6;
    const float* Af = (const float*)Ap;
    const int r = tid >> 2;
    const int c0 = (tid & 3) << 4;
    const float* s = Af + (size_t)(m0 + r) * K + kofs + c0;
    float4 x0 = ((const float4*)s)[0], x1 = ((const float4*)s)[1];
    float4 x2 = ((const float4*)s)[2], x3 = ((const float4*)s)[3];
    const int cc = (tid & 3) << 1;
    *(bf16x8*)&As[buf][(r << 6) + ((cc ^ (r & 7)) << 3)]       = cvt8(x0, x1);
    *(bf16x8*)&As[buf][(r << 6) + (((cc + 1) ^ (r & 7)) << 3)] = cvt8(x2, x3);
  };
  auto read_a = [&](int buf, bf16x8* a) {
#pragma unroll
    for (int m = 0; m < 4; ++m) {
      const int r = (wm << 6) + (m << 4) + lr;
      a[m] = *(const bf16x8*)&As[buf][(r << 6) + ((lc ^ (r & 7)) << 3)];
    }
  };
  auto read_b2 = [&](int buf, int nh, bf16x8* b) {
#pragma unroll
    for (int i = 0; i < 2; ++i) {
      const int r = (wn << 6) + (((nh << 1) + i) << 4) + lr;
      b[i] = *(const bf16x8*)&Bs[buf][(r << 6) + ((lc ^ (r & 7)) << 3)];
    }
  };
  auto mfma8 = [&](bf16x8* a, bf16x8* b, int nh) {
#pragma unroll
    for (int m = 0; m < 4; ++m)
#pragma unroll
      for (int i = 0; i < 2; ++i)
        acc[m][(nh << 1) + i] =
            __builtin_amdgcn_mfma_f32_16x16x32_bf16(a[m], b[i], acc[m][(nh << 1) + i], 0, 0, 0);
  };

  if constexpr (A_BF16) {
    stage_a(0, 0); stage_b(0, 0);
    stage_a(1, 1); stage_b(1, 1);
    asm volatile("s_waitcnt vmcnt(4)" ::: "memory");
    __builtin_amdgcn_s_barrier();
    __builtin_amdgcn_sched_barrier(0);
    for (int t = 0; t < nt; ++t) {
      const int cur = t & 3;
      const bool more = (t + 2 < nt);
      bf16x8 a[4], b0[2], b1[2];
      read_a(cur, a);
      read_b2(cur, 0, b0);
      if (more) stage_a((t + 2) & 3, t + 2);
      __builtin_amdgcn_s_barrier();
      asm volatile("s_waitcnt lgkmcnt(0)" ::: "memory");
      __builtin_amdgcn_sched_barrier(0);
      __builtin_amdgcn_s_setprio(1);
      mfma8(a, b0, 0);
      __builtin_amdgcn_s_setprio(0);
      __builtin_amdgcn_sched_barrier(0);
      read_b2(cur, 1, b1);
      if (more) stage_b((t + 2) & 3, t + 2);
      asm volatile("s_waitcnt lgkmcnt(0)" ::: "memory");
      __builtin_amdgcn_sched_barrier(0);
      __builtin_amdgcn_s_setprio(1);
      mfma8(a, b1, 1);
      __builtin_amdgcn_s_setprio(0);
      __builtin_amdgcn_sched_barrier(0);
      if (more)            asm volatile("s_waitcnt vmcnt(4)" ::: "memory");
      else if (t + 1 < nt) asm volatile("s_waitcnt vmcnt(0)" ::: "memory");
      __builtin_amdgcn_s_barrier();
      __builtin_amdgcn_sched_barrier(0);
    }
  } else {
    stage_a_f32(0, 0); stage_b(0, 0);
    stage_a_f32(1, 1); stage_b(1, 1);
    __syncthreads();
    for (int t = 0; t < nt; ++t) {
      const int cur = t & 3;
      if (t + 2 < nt) { stage_a_f32((t + 2) & 3, t + 2); stage_b((t + 2) & 3, t + 2); }
      bf16x8 a[4], b0[2], b1[2];
      read_a(cur, a); read_b2(cur, 0, b0); read_b2(cur, 1, b1);
      __builtin_amdgcn_s_setprio(1);
      mfma8(a, b0, 0); mfma8(a, b1, 1);
      __builtin_amdgcn_s_setprio(0);
      __syncthreads();
    }
  }

  __syncthreads();
  float* red = (float*)&As[0][0];
  if (w >= 4) {
    float* my = red + ((w - 4) << 12);
#pragma unroll
    for (int m = 0; m < 4; ++m)
#pragma unroll
      for (int n = 0; n < 4; ++n)
        *(f32x4*)&my[(((m << 2) + n) << 8) + (lane << 2)] = acc[m][n];
  }
  __syncthreads();
  if (w < 4) {
    float* my = red + (w << 12);
#pragma unroll
    for (int m = 0; m < 4; ++m)
#pragma unroll
      for (int n = 0; n < 4; ++n)
        acc[m][n] += *(const f32x4*)&my[(((m << 2) + n) << 8) + (lane << 2)];
    const int cl = lane & 15, rg = lane >> 4;
#pragma unroll
    for (int m = 0; m < 4; ++m)
#pragma unroll
      for (int n = 0; n < 4; ++n)
#pragma unroll
        for (int j = 0; j < 4; ++j) {
          const int gi = m0 + (wm << 6) + (m << 4) + (rg << 2) + j;
          const int gn = n0 + (wn << 6) + (n << 4) + cl;
          const float v = acc[m][n][j];
          if constexpr (GCN_EPI) {
            const float d = dinv[gi];
            const float hv = d * v + d * d * feat[(size_t)gi * NF + gn];
            ((unsigned short*)Cp)[(size_t)gi * N + gn] = f2bf_bits(hv);
          } else {
            ((float*)Cp)[(size_t)gi * N + gn] = v;
          }
        }
  }
}

extern "C" void kernel_launch(void* const* d_in, const int* in_sizes, int n_in,
                              void* d_out, int out_size, void* d_ws, size_t ws_size,
                              hipStream_t stream) {
  const float* adj  = (const float*)d_in[0];
  const float* feat = (const float*)d_in[1];
  const float* W    = (const float*)d_in[2];

  // ws: dinv 32KB | FbT 8MB | WbT 512KB | Hb 8MB | adjb 128MB | partials 64MB
  char* ws = (char*)d_ws;
  float* dinv = (float*)ws;
  short* FbT  = (short*)(ws + 32768);
  short* WbT  = (short*)(ws + 32768 + 8388608);
  short* Hb   = (short*)(ws + 32768 + 8388608 + 524288);
  short* adjb = (short*)(ws + 32768 + 8388608 + 524288 + 8388608);
  float* part = (float*)(ws + 32768 + 8388608 + 524288 + 8388608 + 134217728);
  float* out  = (float*)d_out;
  const size_t need = (size_t)32768 + 8388608 + 524288 + 8388608 + 134217728 +
                      (size_t)SPLITK * NN * NF * 4;
  const bool big_ws = ws_size >= need;

  if (big_ws) {
    k_rowsum<true><<<NN, 256, 0, stream>>>(adj, dinv, adjb);
  } else {
    k_rowsum<false><<<NN, 256, 0, stream>>>(adj, dinv, nullptr);
  }
  k_transpose<true ><<<dim3(NF / 32, NN / 32), 256, 0, stream>>>(feat, NN, NF, dinv, FbT);
  k_transpose<false><<<dim3(NF / 32, NF / 32), 256, 0, stream>>>(W, NF, NF, nullptr, WbT);

  if (big_ws) {
    k_gemm8<<<dim3(NF / 256, NN / 256, SPLITK), 512, 0, stream>>>(adjb, FbT, NF, NN, part);
    k_reduce<<<(NN * NF) / (256 * 4), 256, 0, stream>>>(part, dinv, feat, Hb);
  } else {
    k_gemm2<false, true><<<dim3(NF / 128, NN / 128), 512, 0, stream>>>(
        adj, FbT, NF, NN, dinv, feat, Hb);
  }
  k_gemm2<true, false><<<dim3(NF / 128, NN / 128), 512, 0, stream>>>(
      Hb, WbT, NF, NF, nullptr, nullptr, out);
}

// Round 6
// 169.855 us; speedup vs baseline: 1.2790x; 1.1452x over previous
//
#include <hip/hip_runtime.h>
#include <cstdint>
#include <cstddef>

#define NN 8192
#define NF 512
#define SPLITK 4

typedef __attribute__((ext_vector_type(8))) short bf16x8;
typedef __attribute__((ext_vector_type(8))) unsigned short u16x8;
typedef __attribute__((ext_vector_type(4))) float f32x4;

__device__ __forceinline__ unsigned short f2bf_bits(float f) {
  unsigned u = __builtin_bit_cast(unsigned, f);
  u += 0x7FFFu + ((u >> 16) & 1u);   // round-to-nearest-even
  return (unsigned short)(u >> 16);
}

__device__ __forceinline__ float bf2f(unsigned short b) {
  return __builtin_bit_cast(float, (unsigned)b << 16);
}

__device__ __forceinline__ bf16x8 cvt8(float4 a, float4 b) {
  bf16x8 r;
  r[0] = (short)f2bf_bits(a.x); r[1] = (short)f2bf_bits(a.y);
  r[2] = (short)f2bf_bits(a.z); r[3] = (short)f2bf_bits(a.w);
  r[4] = (short)f2bf_bits(b.x); r[5] = (short)f2bf_bits(b.y);
  r[6] = (short)f2bf_bits(b.z); r[7] = (short)f2bf_bits(b.w);
  return r;
}

__device__ __forceinline__ void gld_lds16(const void* g, void* l) {
  __builtin_amdgcn_global_load_lds(
      (const __attribute__((address_space(1))) unsigned int*)g,
      (__attribute__((address_space(3))) unsigned int*)l, 16, 0, 0);
}

// K0: deg[i] = 1 + sum_j adj[i][j]; dinv = rsqrt(deg). CVT: also write adj as bf16.
template <bool CVT>
__global__ void k_rowsum(const float* __restrict__ adj, float* __restrict__ dinv,
                         short* __restrict__ adjb) {
  const int row = blockIdx.x;
  const float4* p = (const float4*)(adj + (size_t)row * NN);
  short* ob = CVT ? (adjb + (size_t)row * NN) : nullptr;
  float s = 0.f;
#pragma unroll
  for (int j = 0; j < 8; ++j) {
    float4 v = p[j * 256 + threadIdx.x];
    s += (v.x + v.y) + (v.z + v.w);
    if (CVT) {
      ushort4 o;
      o.x = f2bf_bits(v.x); o.y = f2bf_bits(v.y);
      o.z = f2bf_bits(v.z); o.w = f2bf_bits(v.w);
      *(ushort4*)&ob[(size_t)(j * 256 + threadIdx.x) * 4] = o;
    }
  }
#pragma unroll
  for (int off = 32; off > 0; off >>= 1) s += __shfl_down(s, off, 64);
  __shared__ float red[4];
  if ((threadIdx.x & 63) == 0) red[threadIdx.x >> 6] = s;
  __syncthreads();
  if (threadIdx.x == 0) {
    float deg = red[0] + red[1] + red[2] + red[3] + 1.0f;
    dinv[row] = (deg > 0.f) ? (1.0f / sqrtf(deg)) : 0.f;
  }
}

// K2: transpose fp32 [rows][cols] -> bf16 [cols][rows]; optional row-scale by dinv[row]
template <bool SCALE>
__global__ void k_transpose(const float* __restrict__ src, int rows, int cols,
                            const float* __restrict__ dinv, short* __restrict__ dst) {
  __shared__ float tile[32][33];
  const int c0 = blockIdx.x * 32, r0 = blockIdx.y * 32;
  const int tx = threadIdx.x & 31, ty = threadIdx.x >> 5;
#pragma unroll
  for (int i = 0; i < 32; i += 8) {
    float v = src[(size_t)(r0 + ty + i) * cols + c0 + tx];
    if (SCALE) v *= dinv[r0 + ty + i];
    tile[ty + i][tx] = v;
  }
  __syncthreads();
#pragma unroll
  for (int i = 0; i < 32; i += 8)
    dst[(size_t)(c0 + ty + i) * rows + r0 + tx] = (short)f2bf_bits(tile[tx][ty + i]);
}

// k_gemm8 v2: 256x256 split-K GEMM, 512 thr / 8 waves (2M x 4N), BK=64.
// A ring-3 (2-K-tile prefetch lead), B ring-2 (4-phase lead); LDS = 160 KB.
// ONE vmcnt(4) + ONE s_barrier per K-tile (FIFO = [A(t),B(t),A(t+1)] at P0).
// XCD-pair swizzle: hid&7 = XCD (assumed); both n-tiles of an (m,kz) A-panel on
// the same XCD in adjacent rounds -> 2nd A read L2-hits; per-XCD B slice 2MB L2-fits.
// Partials written bf16.
__global__ __launch_bounds__(512, 1)
void k_gemm8(const short* __restrict__ Ab, const short* __restrict__ Bt,
             int N, int K, unsigned short* __restrict__ Pout) {
  __shared__ __align__(16) short As[3][2][256 * 32];   // 96 KB
  __shared__ __align__(16) short Bs[2][2][256 * 32];   // 64 KB
  const int tid = threadIdx.x, lane = tid & 63, w = tid >> 6;
  const int wm = w >> 2, wn = w & 3;           // 2M x 4N wave grid

  // XCD-pair remap (bijective on 256 blocks, grid (2,32,4))
  const int hid = (blockIdx.z * gridDim.y + blockIdx.y) * gridDim.x + blockIdx.x;
  const int xcd = hid & 7, rr = hid >> 3;      // round 0..31
  const int pair = xcd * 16 + (rr >> 1);       // 0..127
  const int member = rr & 1;
  const int m0 = (pair & 31) * 256;
  const int n0 = member * 256;
  const int kz = pair >> 5;
  const int ksl = K / SPLITK;
  const int kbase = kz * ksl;
  const int nt = ksl >> 6;                     // 32
  unsigned short* Cp = Pout + (size_t)kz * ((size_t)NN * (size_t)N);

  f32x4 acc[8][4];
#pragma unroll
  for (int m = 0; m < 8; ++m)
#pragma unroll
    for (int n = 0; n < 4; ++n) acc[m][n] = (f32x4){0.f, 0.f, 0.f, 0.f};

  const int lr = lane & 15, kg = lane >> 4;

  auto stageA = [&](int buf, int t) {          // 4 gld_lds per wave (h0,h1)
#pragma unroll
    for (int h = 0; h < 2; ++h) {
      const int kofs = kbase + (t << 6) + (h << 5) + ((lane & 3) << 3);
#pragma unroll
      for (int rnd = 0; rnd < 2; ++rnd) {
        const int rowb = (rnd << 7) + (w << 4);              // wave-uniform
        const int row = rowb + (lane >> 2);
        gld_lds16(Ab + (size_t)(m0 + row) * K + kofs, &As[buf][h][rowb << 5]);
      }
    }
  };
  auto stageB = [&](int buf, int t) {
#pragma unroll
    for (int h = 0; h < 2; ++h) {
      const int kofs = kbase + (t << 6) + (h << 5) + ((lane & 3) << 3);
#pragma unroll
      for (int rnd = 0; rnd < 2; ++rnd) {
        const int rowb = (rnd << 7) + (w << 4);
        const int row = rowb + (lane >> 2);
        gld_lds16(Bt + (size_t)(n0 + row) * K + kofs, &Bs[buf][h][rowb << 5]);
      }
    }
  };
  auto readA = [&](int buf, int kh, bf16x8* a) {
#pragma unroll
    for (int mf = 0; mf < 8; ++mf)
      a[mf] = *(const bf16x8*)&As[buf][kh][(((wm << 7) + (mf << 4) + lr) << 5) + (kg << 3)];
  };
  auto readB2 = [&](int buf, int kh, int nh, bf16x8* b) {
#pragma unroll
    for (int i = 0; i < 2; ++i)
      b[i] = *(const bf16x8*)&Bs[buf][kh][(((wn << 6) + (((nh << 1) + i) << 4) + lr) << 5) + (kg << 3)];
  };
  auto mfma16 = [&](bf16x8* a, bf16x8* b, int nh) {
#pragma unroll
    for (int mf = 0; mf < 8; ++mf)
#pragma unroll
      for (int i = 0; i < 2; ++i)
        acc[mf][(nh << 1) + i] =
            __builtin_amdgcn_mfma_f32_16x16x32_bf16(a[mf], b[i], acc[mf][(nh << 1) + i], 0, 0, 0);
  };

  // prologue FIFO: [A(0):4, B(0):4, A(1):4]
  stageA(0, 0);
  stageB(0, 0);
  stageA(1, 1);

  for (int t = 0; t < nt; ++t) {
    const int ab = t % 3, bb = t & 1;
    bf16x8 a[8], b0[2], b1[2];
    // ---- tile sync point: drain A(t)+B(t), keep A(t+1) in flight ----
    if (t + 1 < nt) asm volatile("s_waitcnt vmcnt(4)" ::: "memory");
    else            asm volatile("s_waitcnt vmcnt(0)" ::: "memory");
    __builtin_amdgcn_s_barrier();
    __builtin_amdgcn_sched_barrier(0);
    // ---- P0: khalf0, n01 ; issue B(t+1) ----
    readA(ab, 0, a);
    readB2(bb, 0, 0, b0);
    if (t + 1 < nt) stageB((t + 1) & 1, t + 1);
    asm volatile("s_waitcnt lgkmcnt(0)" ::: "memory");
    __builtin_amdgcn_sched_barrier(0);
    __builtin_amdgcn_s_setprio(1);
    mfma16(a, b0, 0);
    __builtin_amdgcn_s_setprio(0);
    __builtin_amdgcn_sched_barrier(0);
    // ---- P1: khalf0, n23 ----
    readB2(bb, 0, 1, b1);
    asm volatile("s_waitcnt lgkmcnt(0)" ::: "memory");
    __builtin_amdgcn_sched_barrier(0);
    __builtin_amdgcn_s_setprio(1);
    mfma16(a, b1, 1);
    __builtin_amdgcn_s_setprio(0);
    __builtin_amdgcn_sched_barrier(0);
    // ---- P2: khalf1, n01 ; issue A(t+2) ----
    readA(ab, 1, a);
    readB2(bb, 1, 0, b0);
    if (t + 2 < nt) stageA((t + 2) % 3, t + 2);
    asm volatile("s_waitcnt lgkmcnt(0)" ::: "memory");
    __builtin_amdgcn_sched_barrier(0);
    __builtin_amdgcn_s_setprio(1);
    mfma16(a, b0, 0);
    __builtin_amdgcn_s_setprio(0);
    __builtin_amdgcn_sched_barrier(0);
    // ---- P3: khalf1, n23 ----
    readB2(bb, 1, 1, b1);
    asm volatile("s_waitcnt lgkmcnt(0)" ::: "memory");
    __builtin_amdgcn_sched_barrier(0);
    __builtin_amdgcn_s_setprio(1);
    mfma16(a, b1, 1);
    __builtin_amdgcn_s_setprio(0);
    __builtin_amdgcn_sched_barrier(0);
  }

  // epilogue: C/D layout col=lane&15, row=(lane>>4)*4+j ; bf16 partial store
  const int cl = lane & 15, rg = lane >> 4;
#pragma unroll
  for (int mf = 0; mf < 8; ++mf)
#pragma unroll
    for (int nf = 0; nf < 4; ++nf)
#pragma unroll
      for (int j = 0; j < 4; ++j) {
        const int gi = m0 + (wm << 7) + (mf << 4) + (rg << 2) + j;
        const int gn = n0 + (wn << 6) + (nf << 4) + cl;
        Cp[(size_t)gi * N + gn] = f2bf_bits(acc[mf][nf][j]);
      }
}

// k_reduce: Hb[i][n] = bf16( d_i * sum_kz Pb[kz][i][n] + d_i^2 * feat[i][n] )
__global__ void k_reduce(const unsigned short* __restrict__ P, const float* __restrict__ dinv,
                         const float* __restrict__ feat, short* __restrict__ Hb) {
  const size_t idx = ((size_t)blockIdx.x * 256 + threadIdx.x) * 8;
  const int i = (int)(idx >> 9);
  const size_t stride = (size_t)NN * NF;
  float s[8] = {0.f, 0.f, 0.f, 0.f, 0.f, 0.f, 0.f, 0.f};
#pragma unroll
  for (int kz = 0; kz < SPLITK; ++kz) {
    u16x8 v = *(const u16x8*)&P[kz * stride + idx];
#pragma unroll
    for (int j = 0; j < 8; ++j) s[j] += bf2f(v[j]);
  }
  const float d = dinv[i], d2 = d * d;
  float4 f0 = *(const float4*)&feat[idx];
  float4 f1 = *(const float4*)&feat[idx + 4];
  u16x8 o;
  o[0] = f2bf_bits(d * s[0] + d2 * f0.x);
  o[1] = f2bf_bits(d * s[1] + d2 * f0.y);
  o[2] = f2bf_bits(d * s[2] + d2 * f0.z);
  o[3] = f2bf_bits(d * s[3] + d2 * f0.w);
  o[4] = f2bf_bits(d * s[4] + d2 * f1.x);
  o[5] = f2bf_bits(d * s[5] + d2 * f1.y);
  o[6] = f2bf_bits(d * s[6] + d2 * f1.z);
  o[7] = f2bf_bits(d * s[7] + d2 * f1.w);
  *(u16x8*)&Hb[idx] = o;
}

// k_gemm2: 8-wave pipelined 128x128 GEMM (round-3 version) for GEMM2 (K=512)
// and the no-workspace fallback for GEMM1.
template <bool A_BF16, bool GCN_EPI>
__global__ __launch_bounds__(512, 2)
void k_gemm2(const void* __restrict__ Ap, const short* __restrict__ Bt,
             int N, int K,
             const float* __restrict__ dinv, const float* __restrict__ feat,
             void* __restrict__ Cp) {
  __shared__ __align__(16) short As[4][128 * 64];
  __shared__ __align__(16) short Bs[4][128 * 64];
  const int tid = threadIdx.x;
  const int lane = tid & 63;
  const int w = tid >> 6;
  const int wm = (w >> 1) & 1, wn = w & 1, kk = w >> 2;

  const int bid = blockIdx.y * gridDim.x + blockIdx.x;
  const int nb = gridDim.x * gridDim.y;
  const int sbid = ((nb & 7) == 0) ? ((bid & 7) * (nb >> 3) + (bid >> 3)) : bid;
  const int n0 = (sbid % gridDim.x) * 128;
  const int m0 = (sbid / gridDim.x) * 128;
  const int nt = K >> 6;

  f32x4 acc[4][4];
#pragma unroll
  for (int m = 0; m < 4; ++m)
#pragma unroll
    for (int n = 0; n < 4; ++n) acc[m][n] = (f32x4){0.f, 0.f, 0.f, 0.f};

  const int lr = lane & 15, kg = lane >> 4;
  const int lc = (kk << 2) + kg;

  auto stage_b = [&](int buf, int t) {
    const int kofs = t << 6;
#pragma unroll
    for (int q = 0; q < 2; ++q) {
      const int rblk = (w << 4) + (q << 3);
      const int r = rblk + (lane >> 3);
      const int sc = (lane & 7) ^ (r & 7);
      gld_lds16(Bt + (size_t)(n0 + r) * K + kofs + (sc << 3), &Bs[buf][rblk << 6]);
    }
  };
  auto stage_a = [&](int buf, int t) {
    const int kofs = t << 6;
    const short* Ab = (const short*)Ap;
#pragma unroll
    for (int q = 0; q < 2; ++q) {
      const int rblk = (w << 4) + (q << 3);
      const int r = rblk + (lane >> 3);
      const int sc = (lane & 7) ^ (r & 7);
      gld_lds16(Ab + (size_t)(m0 + r) * K + kofs + (sc << 3), &As[buf][rblk << 6]);
    }
  };
  auto stage_a_f32 = [&](int buf, int t) {
    const int kofs = t << 6;
    const float* Af = (const float*)Ap;
    const int r = tid >> 2;
    const int c0 = (tid & 3) << 4;
    const float* s = Af + (size_t)(m0 + r) * K + kofs + c0;
    float4 x0 = ((const float4*)s)[0], x1 = ((const float4*)s)[1];
    float4 x2 = ((const float4*)s)[2], x3 = ((const float4*)s)[3];
    const int cc = (tid & 3) << 1;
    *(bf16x8*)&As[buf][(r << 6) + ((cc ^ (r & 7)) << 3)]       = cvt8(x0, x1);
    *(bf16x8*)&As[buf][(r << 6) + (((cc + 1) ^ (r & 7)) << 3)] = cvt8(x2, x3);
  };
  auto read_a = [&](int buf, bf16x8* a) {
#pragma unroll
    for (int m = 0; m < 4; ++m) {
      const int r = (wm << 6) + (m << 4) + lr;
      a[m] = *(const bf16x8*)&As[buf][(r << 6) + ((lc ^ (r & 7)) << 3)];
    }
  };
  auto read_b2 = [&](int buf, int nh, bf16x8* b) {
#pragma unroll
    for (int i = 0; i < 2; ++i) {
      const int r = (wn << 6) + (((nh << 1) + i) << 4) + lr;
      b[i] = *(const bf16x8*)&Bs[buf][(r << 6) + ((lc ^ (r & 7)) << 3)];
    }
  };
  auto mfma8 = [&](bf16x8* a, bf16x8* b, int nh) {
#pragma unroll
    for (int m = 0; m < 4; ++m)
#pragma unroll
      for (int i = 0; i < 2; ++i)
        acc[m][(nh << 1) + i] =
            __builtin_amdgcn_mfma_f32_16x16x32_bf16(a[m], b[i], acc[m][(nh << 1) + i], 0, 0, 0);
  };

  if constexpr (A_BF16) {
    stage_a(0, 0); stage_b(0, 0);
    stage_a(1, 1); stage_b(1, 1);
    asm volatile("s_waitcnt vmcnt(4)" ::: "memory");
    __builtin_amdgcn_s_barrier();
    __builtin_amdgcn_sched_barrier(0);
    for (int t = 0; t < nt; ++t) {
      const int cur = t & 3;
      const bool more = (t + 2 < nt);
      bf16x8 a[4], b0[2], b1[2];
      read_a(cur, a);
      read_b2(cur, 0, b0);
      if (more) stage_a((t + 2) & 3, t + 2);
      __builtin_amdgcn_s_barrier();
      asm volatile("s_waitcnt lgkmcnt(0)" ::: "memory");
      __builtin_amdgcn_sched_barrier(0);
      __builtin_amdgcn_s_setprio(1);
      mfma8(a, b0, 0);
      __builtin_amdgcn_s_setprio(0);
      __builtin_amdgcn_sched_barrier(0);
      read_b2(cur, 1, b1);
      if (more) stage_b((t + 2) & 3, t + 2);
      asm volatile("s_waitcnt lgkmcnt(0)" ::: "memory");
      __builtin_amdgcn_sched_barrier(0);
      __builtin_amdgcn_s_setprio(1);
      mfma8(a, b1, 1);
      __builtin_amdgcn_s_setprio(0);
      __builtin_amdgcn_sched_barrier(0);
      if (more)            asm volatile("s_waitcnt vmcnt(4)" ::: "memory");
      else if (t + 1 < nt) asm volatile("s_waitcnt vmcnt(0)" ::: "memory");
      __builtin_amdgcn_s_barrier();
      __builtin_amdgcn_sched_barrier(0);
    }
  } else {
    stage_a_f32(0, 0); stage_b(0, 0);
    stage_a_f32(1, 1); stage_b(1, 1);
    __syncthreads();
    for (int t = 0; t < nt; ++t) {
      const int cur = t & 3;
      if (t + 2 < nt) { stage_a_f32((t + 2) & 3, t + 2); stage_b((t + 2) & 3, t + 2); }
      bf16x8 a[4], b0[2], b1[2];
      read_a(cur, a); read_b2(cur, 0, b0); read_b2(cur, 1, b1);
      __builtin_amdgcn_s_setprio(1);
      mfma8(a, b0, 0); mfma8(a, b1, 1);
      __builtin_amdgcn_s_setprio(0);
      __syncthreads();
    }
  }

  __syncthreads();
  float* red = (float*)&As[0][0];
  if (w >= 4) {
    float* my = red + ((w - 4) << 12);
#pragma unroll
    for (int m = 0; m < 4; ++m)
#pragma unroll
      for (int n = 0; n < 4; ++n)
        *(f32x4*)&my[(((m << 2) + n) << 8) + (lane << 2)] = acc[m][n];
  }
  __syncthreads();
  if (w < 4) {
    float* my = red + (w << 12);
#pragma unroll
    for (int m = 0; m < 4; ++m)
#pragma unroll
      for (int n = 0; n < 4; ++n)
        acc[m][n] += *(const f32x4*)&my[(((m << 2) + n) << 8) + (lane << 2)];
    const int cl = lane & 15, rg = lane >> 4;
#pragma unroll
    for (int m = 0; m < 4; ++m)
#pragma unroll
      for (int n = 0; n < 4; ++n)
#pragma unroll
        for (int j = 0; j < 4; ++j) {
          const int gi = m0 + (wm << 6) + (m << 4) + (rg << 2) + j;
          const int gn = n0 + (wn << 6) + (n << 4) + cl;
          const float v = acc[m][n][j];
          if constexpr (GCN_EPI) {
            const float d = dinv[gi];
            const float hv = d * v + d * d * feat[(size_t)gi * NF + gn];
            ((unsigned short*)Cp)[(size_t)gi * N + gn] = f2bf_bits(hv);
          } else {
            ((float*)Cp)[(size_t)gi * N + gn] = v;
          }
        }
  }
}

extern "C" void kernel_launch(void* const* d_in, const int* in_sizes, int n_in,
                              void* d_out, int out_size, void* d_ws, size_t ws_size,
                              hipStream_t stream) {
  const float* adj  = (const float*)d_in[0];
  const float* feat = (const float*)d_in[1];
  const float* W    = (const float*)d_in[2];

  // ws: dinv 32KB | FbT 8MB | WbT 512KB | Hb 8MB | adjb 128MB | partials bf16 32MB
  char* ws = (char*)d_ws;
  float* dinv = (float*)ws;
  short* FbT  = (short*)(ws + 32768);
  short* WbT  = (short*)(ws + 32768 + 8388608);
  short* Hb   = (short*)(ws + 32768 + 8388608 + 524288);
  short* adjb = (short*)(ws + 32768 + 8388608 + 524288 + 8388608);
  unsigned short* part = (unsigned short*)(ws + 32768 + 8388608 + 524288 + 8388608 + 134217728);
  float* out  = (float*)d_out;
  const size_t need = (size_t)32768 + 8388608 + 524288 + 8388608 + 134217728 +
                      (size_t)SPLITK * NN * NF * 2;
  const bool big_ws = ws_size >= need;

  if (big_ws) {
    k_rowsum<true><<<NN, 256, 0, stream>>>(adj, dinv, adjb);
  } else {
    k_rowsum<false><<<NN, 256, 0, stream>>>(adj, dinv, nullptr);
  }
  k_transpose<true ><<<dim3(NF / 32, NN / 32), 256, 0, stream>>>(feat, NN, NF, dinv, FbT);
  k_transpose<false><<<dim3(NF / 32, NF / 32), 256, 0, stream>>>(W, NF, NF, nullptr, WbT);

  if (big_ws) {
    k_gemm8<<<dim3(NF / 256, NN / 256, SPLITK), 512, 0, stream>>>(adjb, FbT, NF, NN, part);
    k_reduce<<<(NN * NF) / (256 * 8), 256, 0, stream>>>(part, dinv, feat, Hb);
  } else {
    k_gemm2<false, true><<<dim3(NF / 128, NN / 128), 512, 0, stream>>>(
        adj, FbT, NF, NN, dinv, feat, Hb);
  }
  k_gemm2<true, false><<<dim3(NF / 128, NN / 128), 512, 0, stream>>>(
      Hb, WbT, NF, NF, nullptr, nullptr, out);
}